// Round 15
// baseline (318.882 us; speedup 1.0000x reference)
//
#include <hip/hip_runtime.h>
#include <hip/hip_bf16.h>
#include <hip/hip_fp16.h>
#include <hip/hip_fp8.h>

#define NN 50000
#define NE 800000
#define NG 64
#define DH 128

#define SEG 64                           // fixed csr slots per node (max deg+1)
#define GEMMB 782                        // GEMM blocks: 3128 waves >= 3125 tiles -> 1 tile/wave (no 2-tile tail)
#define GEMMW (GEMMB * 4)
#define CST 136                          // bf16 epilogue LDS row stride (ushorts)
#define CSTB 136                         // fp8 epilogue LDS row stride (bytes)
#define SMEM_BYTES 17408                 // gemm bf16 epilogue (4 waves * 16 * 136 * 2)
#define NPAIR (NN / 2)                   // aggr: 2 nodes per wave
#define NXCD 8
#define XNODES (NN / NXCD)               // 6250 nodes per XCD slice
#define CHUNKE 4096                      // edges per chunk
#define NCHUNK ((NE + CHUNKE - 1) / CHUNKE)          // 196
#define SCATB (NCHUNK * NXCD)            // 1568 scatter blocks (8 XCD copies/chunk)
#define WTB 256                          // weight transpose blocks (4 matrices)
#define INITB ((NN + 255) / 256)         // 196 self-loop init blocks
#define PREPB (SCATB + WTB + INITB)      // 2020

#if defined(__has_builtin)
# if __has_builtin(__builtin_amdgcn_cvt_pk_f32_fp8) && __has_builtin(__builtin_amdgcn_cvt_pk_fp8_f32)
#  define HW_FP8 1
# endif
#endif

typedef __bf16 bfx8 __attribute__((ext_vector_type(8)));
typedef float  f32x4 __attribute__((ext_vector_type(4)));
typedef float  f32x8 __attribute__((ext_vector_type(8)));
typedef short  s16x8 __attribute__((ext_vector_type(8)));

__device__ __forceinline__ ushort f2b(float f) {        // fp32 -> bf16 RNE
    unsigned b = __float_as_uint(f);
    b += 0x7fff + ((b >> 16) & 1);
    return (ushort)(b >> 16);
}
__device__ __forceinline__ float b2f(ushort s) {
    return __uint_as_float((unsigned)s << 16);
}
__device__ __forceinline__ unsigned pk2(float a, float b) {
    return (unsigned)f2b(a) | ((unsigned)f2b(b) << 16);
}

__device__ __forceinline__ unsigned f2fp8(float v) {    // fp32 -> e4m3 (clamped)
    v = fminf(fmaxf(v, -448.f), 448.f);
#ifdef HW_FP8
    return (unsigned)__builtin_amdgcn_cvt_pk_fp8_f32(v, v, 0, false) & 0xFFu;
#else
    __hip_fp8_e4m3 t(v);
    return (unsigned)*(const unsigned char*)&t;
#endif
}
// unpack 4 e4m3 (in a dword) -> 4 floats
__device__ __forceinline__ void fp8x4_up(unsigned u, float* o) {
#ifdef HW_FP8
    auto lo = __builtin_amdgcn_cvt_pk_f32_fp8((int)u, false);
    auto hi = __builtin_amdgcn_cvt_pk_f32_fp8((int)u, true);
    o[0] = lo[0]; o[1] = lo[1]; o[2] = hi[0]; o[3] = hi[1];
#else
    #pragma unroll
    for (int k = 0; k < 4; ++k) {
        unsigned char c = (u >> (8 * k)) & 0xFF;
        o[k] = float(*(const __hip_fp8_e4m3*)&c);
    }
#endif
}

// ---------------- fused prep: XCD-local scatter | weight prep | init -------
// Scatter with XCD-locality (proven round-12 form): 8 block-copies per edge
// chunk; block (chunk,xcd) handles only edges whose dst falls in xcd's slice
// (xcd = bid&7 dispatch heuristic). 4-deep dst scan keeps the 8x re-reads
// L3-resident (16-deep batching thrashed L3: FETCH 3.5MB -> 25MB, regressed).
__launch_bounds__(256)
__global__ void k_prep(const int* __restrict__ ei, int* __restrict__ cur,
                       ushort* __restrict__ csr,
                       const float* __restrict__ W0, const float* __restrict__ Wc,
                       ushort* __restrict__ Wt) {
    int t = threadIdx.x;
    unsigned bid = blockIdx.x;
    if (bid < SCATB) {
        int chunk = bid >> 3;
        int lo = (int)(bid & 7) * XNODES;
        int base = chunk * CHUNKE + t;               // + j*256, 16 edges/thread
        #pragma unroll
        for (int jj = 0; jj < 16; jj += 4) {
            int dd[4], ee[4];
            #pragma unroll
            for (int q = 0; q < 4; ++q) {
                ee[q] = base + (jj + q) * 256;
                dd[q] = (ee[q] < NE) ? ei[NE + ee[q]] : -1;
            }
            #pragma unroll
            for (int q = 0; q < 4; ++q) {
                if ((unsigned)(dd[q] - lo) < (unsigned)XNODES) {
                    int s = ei[ee[q]];
                    int slot = atomicAdd(&cur[dd[q]], 1);
                    if (slot < SEG - 1)
                        csr[((size_t)dd[q] << 6) + 1 + slot] = (ushort)s;
                }
            }
        }
        return;
    }
    if (bid < SCATB + WTB) {
        int i = (bid - SCATB) * 256 + t;             // 0 .. 65535
        int m = i >> 14;                             // matrix 0..3
        int r = i & 16383;
        int k = r >> 7, n = r & 127;
        const float* src = (m == 0) ? W0 : (Wc + (size_t)(m - 1) * DH * DH);
        Wt[(size_t)m * DH * DH + n * DH + k] = f2b(src[r]);
        return;
    }
    int n = (bid - SCATB - WTB) * 256 + t;
    if (n < NN) csr[(size_t)n << 6] = (ushort)n;     // self-loop first
}

// ---------------- MFMA GEMM body (shared by fused kernels) ----------------
// B (128x128 bf16 = 32 KB = 128 VGPR) register-resident per wave; one wave
// per 16-row tile (GEMMW=3128 >= 3125: exactly 1 tile/wave, no 2-tile tail).
// D: col=lane&15, row=quad*4+reg (verified m89).
template<bool AF32, bool DOTS, bool OUTFP8>
__device__ __forceinline__ void gemm_body(char* smem, int gblk,
        const void* __restrict__ Av, const ushort* __restrict__ Wt,
        const float* __restrict__ bias, void* __restrict__ C, int relu,
        const float* __restrict__ avs, const float* __restrict__ avd,
        float* __restrict__ asrc, float* __restrict__ adst) {
    const int NT = NN / 16;                           // 3125 tiles (NN % 16 == 0)
    int tid = threadIdx.x;
    int lane = tid & 63;
    int mrow = lane & 15;
    int quad = lane >> 4;
    int wid = (gblk * 256 + tid) >> 6;                // 0 .. GEMMW-1

    bfx8 b[4][8];
    #pragma unroll
    for (int ks = 0; ks < 4; ++ks) {
        int k0 = ks * 32 + quad * 8;
        #pragma unroll
        for (int t = 0; t < 8; ++t)
            b[ks][t] = *(const bfx8*)(Wt + (size_t)(t * 16 + mrow) * DH + k0);
    }
    float av[8], dv[8];
    if (DOTS) {
        #pragma unroll
        for (int t = 0; t < 8; ++t) {
            av[t] = avs[t * 16 + mrow];
            dv[t] = avd[t * 16 + mrow];
        }
    }

    for (int tile = wid; tile < NT; tile += GEMMW) {
        int row0 = tile * 16;
        int arow = row0 + mrow;

        bfx8 a[4];
        if (AF32) {
            f32x8 af[4];
            #pragma unroll
            for (int ks = 0; ks < 4; ++ks)
                af[ks] = *(const f32x8*)((const float*)Av + (size_t)arow * DH + ks * 32 + quad * 8);
            #pragma unroll
            for (int ks = 0; ks < 4; ++ks) {
                union { ushort s[8]; bfx8 v; } u;
                #pragma unroll
                for (int j = 0; j < 8; ++j) u.s[j] = f2b(af[ks][j]);
                a[ks] = u.v;
            }
        } else {
            #pragma unroll
            for (int ks = 0; ks < 4; ++ks)
                a[ks] = *(const bfx8*)((const ushort*)Av + (size_t)arow * DH + ks * 32 + quad * 8);
        }

        f32x4 acc[8];
        #pragma unroll
        for (int t = 0; t < 8; ++t)
            #pragma unroll
            for (int r = 0; r < 4; ++r) acc[t][r] = 0.f;

        #pragma unroll
        for (int ks = 0; ks < 4; ++ks)
            #pragma unroll
            for (int t = 0; t < 8; ++t)
                acc[t] = __builtin_amdgcn_mfma_f32_16x16x32_bf16(a[ks], b[ks][t], acc[t], 0, 0, 0);

        if (OUTFP8) {
            uchar* my = (uchar*)smem + (tid >> 6) * 16 * CSTB;
            #pragma unroll
            for (int t = 0; t < 8; ++t) {
                int col = t * 16 + mrow;
                float bv = bias ? bias[col] : 0.f;
                #pragma unroll
                for (int r = 0; r < 4; ++r) {
                    float v = acc[t][r] + bv;
                    if (relu) v = fmaxf(v, 0.f);
                    my[(quad * 4 + r) * CSTB + col] = (uchar)f2fp8(v);
                }
            }
            #pragma unroll
            for (int i = 0; i < 4; ++i) {
                int idx = i * 64 + lane;          // 16 rows x 16 uint2
                int row = idx >> 4;
                int c8 = idx & 15;
                uint2 u = *(const uint2*)(my + row * CSTB + c8 * 8);
                *(uint2*)((uchar*)C + (size_t)(row0 + row) * DH + c8 * 8) = u;
            }
        } else {
            ushort* my = (ushort*)smem + (tid >> 6) * 16 * CST;
            #pragma unroll
            for (int t = 0; t < 8; ++t) {
                int col = t * 16 + mrow;
                float bv = bias ? bias[col] : 0.f;
                #pragma unroll
                for (int r = 0; r < 4; ++r) {
                    float v = acc[t][r] + bv;
                    if (relu) v = fmaxf(v, 0.f);
                    my[(quad * 4 + r) * CST + col] = f2b(v);
                }
            }
            #pragma unroll
            for (int i = 0; i < 4; ++i) {
                int idx = i * 64 + lane;
                int row = idx >> 4;
                int c16 = idx & 15;
                uint4 u = *(const uint4*)(my + row * CST + c16 * 8);
                *(uint4*)((ushort*)C + (size_t)(row0 + row) * DH + c16 * 8) = u;
            }
        }

        if (DOTS) {
            int orow = row0 + quad * 4;
            #pragma unroll
            for (int r = 0; r < 4; ++r) {
                float ps = 0.f, pd = 0.f;
                #pragma unroll
                for (int t = 0; t < 8; ++t) {
                    ps += acc[t][r] * av[t];
                    pd += acc[t][r] * dv[t];
                }
                #pragma unroll
                for (int off = 1; off < 16; off <<= 1) {
                    ps += __shfl_xor(ps, off);
                    pd += __shfl_xor(pd, off);
                }
                if (mrow == 0) {
                    asrc[orow + r] = ps;
                    adst[orow + r] = pd;
                }
            }
        }
    }
}

// ---------------- GEMM-1: fp32 x -> bf16 hB -------------------------------
__launch_bounds__(256)
__global__ void k_gemm1(const float* __restrict__ x, const ushort* __restrict__ Wt,
                        const float* __restrict__ b0, ushort* __restrict__ hB) {
    __shared__ char smem[SMEM_BYTES];
    gemm_body<true, false, false>(smem, blockIdx.x, x, Wt, b0, hB, 1,
                                  nullptr, nullptr, nullptr, nullptr);
}

// ---------------- GEMM + fused attention dots (layers, fp8 out) ----------
__launch_bounds__(256)
__global__ void k_gemmdots(const ushort* __restrict__ hB, const ushort* __restrict__ Wt,
                           uchar* __restrict__ hA,
                           const float* __restrict__ avs, const float* __restrict__ avd,
                           float* __restrict__ asrc, float* __restrict__ adst) {
    __shared__ char smem[SMEM_BYTES];
    gemm_body<false, true, true>(smem, blockIdx.x, hB, Wt, nullptr, hA, 0,
                                 avs, avd, asrc, adst);
}

// ---------------- single-node aggregate (64-lane, cnt in (32,64]) ----------
__device__ __forceinline__ void aggr_one(int wid, int lane,
        const uchar* __restrict__ h8, const float* __restrict__ asrc,
        const float* __restrict__ adst, const int* __restrict__ cur,
        const ushort* __restrict__ csr,
        const float* __restrict__ bias, ushort* __restrict__ hout) {
    int start = wid << 6;
    int cnt = min(cur[wid] + 1, SEG);
    float ad = adst[wid];

    // masked load: pad lanes use node 0 (w=0 anyway) -> csr pads need no memset
    int s = (lane < cnt) ? (int)csr[start + lane] : 0;
    float e = -1e30f;
    if (lane < cnt) {
        float t = asrc[s] + ad;
        e = fmaxf(t, 0.f) + 0.2f * fminf(t, 0.f);
    }
    float m = e;
    #pragma unroll
    for (int off = 32; off; off >>= 1) m = fmaxf(m, __shfl_xor(m, off));
    float w = (lane < cnt) ? __expf(e - m) : 0.f;
    float dsum = w;
    #pragma unroll
    for (int off = 32; off; off >>= 1) dsum += __shfl_xor(dsum, off);

    int g = lane >> 4, fidx = lane & 15;
    float acc[8];
    #pragma unroll
    for (int k = 0; k < 8; ++k) acc[k] = 0.f;

    int steps = (cnt + 3) >> 2;
    const uint2* hp = (const uint2*)h8;      // 16 uint2 per 128B row
    for (int j = 0; j < steps; ++j) {
        int e0 = j * 4 + g;
        float w0 = __shfl(w, e0);
        int   s0 = __shfl(s, e0);
        uint2 u0 = hp[(size_t)s0 * 16 + fidx];
        float v[8];
        fp8x4_up(u0.x, v); fp8x4_up(u0.y, v + 4);
        #pragma unroll
        for (int k = 0; k < 8; ++k) acc[k] += w0 * v[k];
    }
    #pragma unroll
    for (int k = 0; k < 8; ++k) {
        acc[k] += __shfl_xor(acc[k], 16);
        acc[k] += __shfl_xor(acc[k], 32);
    }
    if (g == 0) {
        float inv = 1.f / (dsum + 1e-16f);
        const float4* bp = (const float4*)bias;
        float4 b0 = bp[fidx * 2], b1 = bp[fidx * 2 + 1];
        uint4 o;
        o.x = pk2(fmaxf(acc[0] * inv + b0.x, 0.f), fmaxf(acc[1] * inv + b0.y, 0.f));
        o.y = pk2(fmaxf(acc[2] * inv + b0.z, 0.f), fmaxf(acc[3] * inv + b0.w, 0.f));
        o.z = pk2(fmaxf(acc[4] * inv + b1.x, 0.f), fmaxf(acc[5] * inv + b1.y, 0.f));
        o.w = pk2(fmaxf(acc[6] * inv + b1.z, 0.f), fmaxf(acc[7] * inv + b1.w, 0.f));
        ((uint4*)hout)[(size_t)wid * 16 + fidx] = o;
    }
}

// ---------------- fused segment softmax + weighted aggregate (fp8 h) -------
// TWO nodes per wave (measured-best round-5 variant): half-wave per node,
// width-32 reductions, 2 gather groups of 16 lanes per half, uint2 gathers
// 4 steps in flight. Rare cnt>32 pairs fall back to the 64-lane path.
__launch_bounds__(256)
__global__ void k_aggr(const uchar* __restrict__ h8, const float* __restrict__ asrc,
                       const float* __restrict__ adst, const int* __restrict__ cur,
                       const ushort* __restrict__ csr,
                       const float* __restrict__ bias, ushort* __restrict__ hout) {
    int pid = (blockIdx.x * blockDim.x + threadIdx.x) >> 6;
    int lane = threadIdx.x & 63;
    if (pid >= NPAIR) return;
    int half = lane >> 5, hl = lane & 31;
    int nd = pid * 2 + half;                     // NN even -> always < NN
    int start = nd << 6;

    int cnt = min(cur[nd] + 1, SEG);
    int cother = __shfl_xor(cnt, 32);            // other half's (uniform) cnt
    if (max(cnt, cother) <= 32) {
        float ad = adst[nd];
        // masked load: pad lanes use node 0 (their w=0) -> no csr memset needed
        int s = (hl < cnt) ? (int)csr[start + hl] : 0;
        float e = -1e30f;
        if (hl < cnt) {
            float t = asrc[s] + ad;
            e = fmaxf(t, 0.f) + 0.2f * fminf(t, 0.f);
        }
        float m = e;
        #pragma unroll
        for (int off = 16; off; off >>= 1) m = fmaxf(m, __shfl_xor(m, off));
        float w = (hl < cnt) ? __expf(e - m) : 0.f;
        float dsum = w;
        #pragma unroll
        for (int off = 16; off; off >>= 1) dsum += __shfl_xor(dsum, off);

        int g = hl >> 4, fidx = hl & 15;         // 2 gather groups per half
        int lbase = half * 32;
        float acc[8];
        #pragma unroll
        for (int k = 0; k < 8; ++k) acc[k] = 0.f;

        int steps = (cnt + 1) >> 1;              // 2 edges/step/node, <=16
        const uint2* hp = (const uint2*)h8;      // 16 uint2 per 128B row
        int j = 0;
        for (; j + 3 < steps; j += 4) {
            int   e0 = j * 2 + g,       e1 = e0 + 2, e2 = e0 + 4, e3 = e0 + 6;
            float w0 = __shfl(w, lbase + e0), w1 = __shfl(w, lbase + e1);
            float w2 = __shfl(w, lbase + e2), w3 = __shfl(w, lbase + e3);
            int   s0 = __shfl(s, lbase + e0), s1 = __shfl(s, lbase + e1);
            int   s2 = __shfl(s, lbase + e2), s3 = __shfl(s, lbase + e3);
            uint2 u0 = hp[(size_t)s0 * 16 + fidx];
            uint2 u1 = hp[(size_t)s1 * 16 + fidx];
            uint2 u2 = hp[(size_t)s2 * 16 + fidx];
            uint2 u3 = hp[(size_t)s3 * 16 + fidx];
            float v[8];
            fp8x4_up(u0.x, v); fp8x4_up(u0.y, v + 4);
            #pragma unroll
            for (int k = 0; k < 8; ++k) acc[k] += w0 * v[k];
            fp8x4_up(u1.x, v); fp8x4_up(u1.y, v + 4);
            #pragma unroll
            for (int k = 0; k < 8; ++k) acc[k] += w1 * v[k];
            fp8x4_up(u2.x, v); fp8x4_up(u2.y, v + 4);
            #pragma unroll
            for (int k = 0; k < 8; ++k) acc[k] += w2 * v[k];
            fp8x4_up(u3.x, v); fp8x4_up(u3.y, v + 4);
            #pragma unroll
            for (int k = 0; k < 8; ++k) acc[k] += w3 * v[k];
        }
        for (; j < steps; ++j) {
            int   e0 = j * 2 + g;
            float w0 = __shfl(w, lbase + e0);
            int   s0 = __shfl(s, lbase + e0);
            uint2 u0 = hp[(size_t)s0 * 16 + fidx];
            float v[8];
            fp8x4_up(u0.x, v); fp8x4_up(u0.y, v + 4);
            #pragma unroll
            for (int k = 0; k < 8; ++k) acc[k] += w0 * v[k];
        }
        #pragma unroll
        for (int k = 0; k < 8; ++k) acc[k] += __shfl_xor(acc[k], 16);   // g0+g1, same half
        if (g == 0) {
            float inv = 1.f / (dsum + 1e-16f);
            const float4* bp = (const float4*)bias;
            float4 b0 = bp[fidx * 2], b1 = bp[fidx * 2 + 1];
            uint4 o;
            o.x = pk2(fmaxf(acc[0] * inv + b0.x, 0.f), fmaxf(acc[1] * inv + b0.y, 0.f));
            o.y = pk2(fmaxf(acc[2] * inv + b0.z, 0.f), fmaxf(acc[3] * inv + b0.w, 0.f));
            o.z = pk2(fmaxf(acc[4] * inv + b1.x, 0.f), fmaxf(acc[5] * inv + b1.y, 0.f));
            o.w = pk2(fmaxf(acc[6] * inv + b1.z, 0.f), fmaxf(acc[7] * inv + b1.w, 0.f));
            ((uint4*)hout)[(size_t)nd * 16 + fidx] = o;
        }
        return;
    }

    // rare: at least one node of the pair exceeds 32 -> sequential 64-lane
    aggr_one(pid * 2,     lane, h8, asrc, adst, cur, csr, bias, hout);
    aggr_one(pid * 2 + 1, lane, h8, asrc, adst, cur, csr, bias, hout);
}

// ---------------- fused mean-pool + final linear (no atomics) --------------
// 64 blocks = 1 graph each. batch is sorted: binary-search the node range,
// reduce 16 rows in flight (short8 loads), LDS-combine, then the 128x10 dot.
__launch_bounds__(256)
__global__ void k_tail(const ushort* __restrict__ h, const int* __restrict__ batch,
                       const float* __restrict__ W1, const float* __restrict__ b1,
                       float* __restrict__ out) {
    __shared__ float sv[16][128];
    int g = blockIdx.x;
    int t = threadIdx.x;

    int a = 0, b = NN;                            // lower_bound(g)
    while (a < b) { int m = (a + b) >> 1; if (batch[m] < g) a = m + 1; else b = m; }
    int lo = a;
    b = NN;                                       // lower_bound(g+1)
    while (a < b) { int m = (a + b) >> 1; if (batch[m] < g + 1) a = m + 1; else b = m; }
    int hi = a;

    int slot = t >> 4;                            // 16 row-slots
    int f8 = (t & 15) * 8;                        // feature group
    float acc[8];
    #pragma unroll
    for (int j = 0; j < 8; ++j) acc[j] = 0.f;
    for (int nd = lo + slot; nd < hi; nd += 16) {
        s16x8 v = *(const s16x8*)(h + (size_t)nd * DH + f8);
        #pragma unroll
        for (int j = 0; j < 8; ++j) acc[j] += b2f((ushort)v[j]);
    }
    #pragma unroll
    for (int j = 0; j < 8; ++j) sv[slot][f8 + j] = acc[j];
    __syncthreads();

    if (t < 128) {
        float s = 0.f;
        #pragma unroll
        for (int k = 0; k < 16; ++k) s += sv[k][t];
        sv[0][t] = s;
    }
    __syncthreads();

    if (t < 10) {
        float inv = 1.f / fmaxf((float)(hi - lo), 1.f);
        float d = 0.f;
        for (int f = 0; f < DH; ++f) d += sv[0][f] * W1[f * 10 + t];
        out[g * 10 + t] = d * inv + b1[t];
    }
}

extern "C" void kernel_launch(void* const* d_in, const int* in_sizes, int n_in,
                              void* d_out, int out_size, void* d_ws, size_t ws_size,
                              hipStream_t stream) {
    const float* x       = (const float*)d_in[0];
    const int*   ei      = (const int*)d_in[1];
    const int*   batch   = (const int*)d_in[3];
    const float* W0      = (const float*)d_in[4];
    const float* b0      = (const float*)d_in[5];
    const float* Wc      = (const float*)d_in[6];
    const float* att_src = (const float*)d_in[7];
    const float* att_dst = (const float*)d_in[8];
    const float* bc      = (const float*)d_in[9];
    const float* W1      = (const float*)d_in[10];
    const float* b1      = (const float*)d_in[11];
    float* out = (float*)d_out;

    char* ws = (char*)d_ws;
    size_t off = 0;
    auto alloc = [&](size_t bytes) {
        void* p = ws + off;
        off += (bytes + 255) & ~(size_t)255;
        return p;
    };
    uchar*    hA     = (uchar*)alloc((size_t)NN * DH);        // fp8 e4m3
    ushort*   hB     = (ushort*)alloc((size_t)NN * DH * 2);   // bf16
    ushort*   Wt     = (ushort*)alloc((size_t)4 * DH * DH * 2);
    ushort*   csr    = (ushort*)alloc((size_t)NN * SEG * 2);  // fixed-stride segments (no memset: pads masked)
    int*      cur    = (int*)alloc((size_t)NN * 4);           // 0-based edge count
    float*    asrc   = (float*)alloc(NN * 4);
    float*    adst   = (float*)alloc(NN * 4);

    hipMemsetAsync(cur, 0, (size_t)NN * 4, stream);           // only cur needs zeroing

    k_prep<<<PREPB, 256, 0, stream>>>(ei, cur, csr, W0, Wc, Wt);
    k_gemm1<<<GEMMB, 256, 0, stream>>>(x, Wt, b0, hB);

    for (int l = 0; l < 3; ++l) {
        k_gemmdots<<<GEMMB, 256, 0, stream>>>(hB, Wt + (size_t)(l + 1) * DH * DH, hA,
                                              att_src + l * DH, att_dst + l * DH,
                                              asrc, adst);
        k_aggr<<<(NPAIR + 3) / 4, 256, 0, stream>>>(hA, asrc, adst, cur, csr,
                                                    bc + l * DH, hB);
    }

    k_tail<<<NG, 256, 0, stream>>>(hB, batch, W1, b1, out);
}

// Round 16
// 296.174 us; speedup vs baseline: 1.0767x; 1.0767x over previous
//
#include <hip/hip_runtime.h>
#include <hip/hip_bf16.h>
#include <hip/hip_fp16.h>
#include <hip/hip_fp8.h>

#define NN 50000
#define NE 800000
#define NG 64
#define DH 128

#define SEG 64                           // fixed csr slots per node (max deg+1)
#define GEMMB 512                        // GEMM blocks: 2 blocks/CU x 256 CU = machine-exact fill (782 regressed: dispatch tail)
#define GEMMW (GEMMB * 4)                // 2048 waves, grid-stride over 3125 tiles
#define CST 136                          // bf16 epilogue LDS row stride (ushorts)
#define CSTB 136                         // fp8 epilogue LDS row stride (bytes)
#define SMEM_BYTES 17408                 // gemm bf16 epilogue (4 waves * 16 * 136 * 2)
#define NPAIR (NN / 2)                   // aggr: 2 nodes per wave
#define NXCD 8
#define XNODES (NN / NXCD)               // 6250 nodes per XCD slice
#define CHUNKE 4096                      // edges per chunk
#define NCHUNK ((NE + CHUNKE - 1) / CHUNKE)          // 196
#define SCATB (NCHUNK * NXCD)            // 1568 scatter blocks (8 XCD copies/chunk)
#define WTB 256                          // weight transpose blocks (4 matrices)
#define INITB ((NN + 255) / 256)         // 196 self-loop init blocks
#define PREPB (SCATB + WTB + INITB)      // 2020

#if defined(__has_builtin)
# if __has_builtin(__builtin_amdgcn_cvt_pk_f32_fp8) && __has_builtin(__builtin_amdgcn_cvt_pk_fp8_f32)
#  define HW_FP8 1
# endif
#endif

typedef __bf16 bfx8 __attribute__((ext_vector_type(8)));
typedef float  f32x4 __attribute__((ext_vector_type(4)));
typedef float  f32x8 __attribute__((ext_vector_type(8)));
typedef short  s16x8 __attribute__((ext_vector_type(8)));

__device__ __forceinline__ ushort f2b(float f) {        // fp32 -> bf16 RNE
    unsigned b = __float_as_uint(f);
    b += 0x7fff + ((b >> 16) & 1);
    return (ushort)(b >> 16);
}
__device__ __forceinline__ float b2f(ushort s) {
    return __uint_as_float((unsigned)s << 16);
}
__device__ __forceinline__ unsigned pk2(float a, float b) {
    return (unsigned)f2b(a) | ((unsigned)f2b(b) << 16);
}

__device__ __forceinline__ unsigned f2fp8(float v) {    // fp32 -> e4m3 (clamped)
    v = fminf(fmaxf(v, -448.f), 448.f);
#ifdef HW_FP8
    return (unsigned)__builtin_amdgcn_cvt_pk_fp8_f32(v, v, 0, false) & 0xFFu;
#else
    __hip_fp8_e4m3 t(v);
    return (unsigned)*(const unsigned char*)&t;
#endif
}
// unpack 4 e4m3 (in a dword) -> 4 floats
__device__ __forceinline__ void fp8x4_up(unsigned u, float* o) {
#ifdef HW_FP8
    auto lo = __builtin_amdgcn_cvt_pk_f32_fp8((int)u, false);
    auto hi = __builtin_amdgcn_cvt_pk_f32_fp8((int)u, true);
    o[0] = lo[0]; o[1] = lo[1]; o[2] = hi[0]; o[3] = hi[1];
#else
    #pragma unroll
    for (int k = 0; k < 4; ++k) {
        unsigned char c = (u >> (8 * k)) & 0xFF;
        o[k] = float(*(const __hip_fp8_e4m3*)&c);
    }
#endif
}

// ---------------- fused prep: XCD-local scatter | weight prep | init -------
// Scatter with XCD-locality (proven round-12 form): 8 block-copies per edge
// chunk; block (chunk,xcd) handles only edges whose dst falls in xcd's slice
// (xcd = bid&7 dispatch heuristic). 4-deep dst scan keeps the 8x re-reads
// L3-resident (16-deep batching thrashed L3: FETCH 3.5MB -> 25MB, regressed).
__launch_bounds__(256)
__global__ void k_prep(const int* __restrict__ ei, int* __restrict__ cur,
                       ushort* __restrict__ csr,
                       const float* __restrict__ W0, const float* __restrict__ Wc,
                       ushort* __restrict__ Wt) {
    int t = threadIdx.x;
    unsigned bid = blockIdx.x;
    if (bid < SCATB) {
        int chunk = bid >> 3;
        int lo = (int)(bid & 7) * XNODES;
        int base = chunk * CHUNKE + t;               // + j*256, 16 edges/thread
        #pragma unroll
        for (int jj = 0; jj < 16; jj += 4) {
            int dd[4], ee[4];
            #pragma unroll
            for (int q = 0; q < 4; ++q) {
                ee[q] = base + (jj + q) * 256;
                dd[q] = (ee[q] < NE) ? ei[NE + ee[q]] : -1;
            }
            #pragma unroll
            for (int q = 0; q < 4; ++q) {
                if ((unsigned)(dd[q] - lo) < (unsigned)XNODES) {
                    int s = ei[ee[q]];
                    int slot = atomicAdd(&cur[dd[q]], 1);
                    if (slot < SEG - 1)
                        csr[((size_t)dd[q] << 6) + 1 + slot] = (ushort)s;
                }
            }
        }
        return;
    }
    if (bid < SCATB + WTB) {
        int i = (bid - SCATB) * 256 + t;             // 0 .. 65535
        int m = i >> 14;                             // matrix 0..3
        int r = i & 16383;
        int k = r >> 7, n = r & 127;
        const float* src = (m == 0) ? W0 : (Wc + (size_t)(m - 1) * DH * DH);
        Wt[(size_t)m * DH * DH + n * DH + k] = f2b(src[r]);
        return;
    }
    int n = (bid - SCATB - WTB) * 256 + t;
    if (n < NN) csr[(size_t)n << 6] = (ushort)n;     // self-loop first
}

// ---------------- MFMA GEMM body (shared by fused kernels) ----------------
// B (128x128 bf16 = 32 KB = 128 VGPR) register-resident per wave; waves
// grid-stride over 16-row tiles (<=2 tiles at GEMMW=2048). K-loop has zero
// loads. D: col=lane&15, row=quad*4+reg (verified m89).
template<bool AF32, bool DOTS, bool OUTFP8>
__device__ __forceinline__ void gemm_body(char* smem, int gblk,
        const void* __restrict__ Av, const ushort* __restrict__ Wt,
        const float* __restrict__ bias, void* __restrict__ C, int relu,
        const float* __restrict__ avs, const float* __restrict__ avd,
        float* __restrict__ asrc, float* __restrict__ adst) {
    const int NT = NN / 16;                           // 3125 tiles (NN % 16 == 0)
    int tid = threadIdx.x;
    int lane = tid & 63;
    int mrow = lane & 15;
    int quad = lane >> 4;
    int wid = (gblk * 256 + tid) >> 6;                // 0 .. GEMMW-1

    bfx8 b[4][8];
    #pragma unroll
    for (int ks = 0; ks < 4; ++ks) {
        int k0 = ks * 32 + quad * 8;
        #pragma unroll
        for (int t = 0; t < 8; ++t)
            b[ks][t] = *(const bfx8*)(Wt + (size_t)(t * 16 + mrow) * DH + k0);
    }
    float av[8], dv[8];
    if (DOTS) {
        #pragma unroll
        for (int t = 0; t < 8; ++t) {
            av[t] = avs[t * 16 + mrow];
            dv[t] = avd[t * 16 + mrow];
        }
    }

    for (int tile = wid; tile < NT; tile += GEMMW) {
        int row0 = tile * 16;
        int arow = row0 + mrow;

        bfx8 a[4];
        if (AF32) {
            f32x8 af[4];
            #pragma unroll
            for (int ks = 0; ks < 4; ++ks)
                af[ks] = *(const f32x8*)((const float*)Av + (size_t)arow * DH + ks * 32 + quad * 8);
            #pragma unroll
            for (int ks = 0; ks < 4; ++ks) {
                union { ushort s[8]; bfx8 v; } u;
                #pragma unroll
                for (int j = 0; j < 8; ++j) u.s[j] = f2b(af[ks][j]);
                a[ks] = u.v;
            }
        } else {
            #pragma unroll
            for (int ks = 0; ks < 4; ++ks)
                a[ks] = *(const bfx8*)((const ushort*)Av + (size_t)arow * DH + ks * 32 + quad * 8);
        }

        f32x4 acc[8];
        #pragma unroll
        for (int t = 0; t < 8; ++t)
            #pragma unroll
            for (int r = 0; r < 4; ++r) acc[t][r] = 0.f;

        #pragma unroll
        for (int ks = 0; ks < 4; ++ks)
            #pragma unroll
            for (int t = 0; t < 8; ++t)
                acc[t] = __builtin_amdgcn_mfma_f32_16x16x32_bf16(a[ks], b[ks][t], acc[t], 0, 0, 0);

        if (OUTFP8) {
            uchar* my = (uchar*)smem + (tid >> 6) * 16 * CSTB;
            #pragma unroll
            for (int t = 0; t < 8; ++t) {
                int col = t * 16 + mrow;
                float bv = bias ? bias[col] : 0.f;
                #pragma unroll
                for (int r = 0; r < 4; ++r) {
                    float v = acc[t][r] + bv;
                    if (relu) v = fmaxf(v, 0.f);
                    my[(quad * 4 + r) * CSTB + col] = (uchar)f2fp8(v);
                }
            }
            #pragma unroll
            for (int i = 0; i < 4; ++i) {
                int idx = i * 64 + lane;          // 16 rows x 16 uint2
                int row = idx >> 4;
                int c8 = idx & 15;
                uint2 u = *(const uint2*)(my + row * CSTB + c8 * 8);
                *(uint2*)((uchar*)C + (size_t)(row0 + row) * DH + c8 * 8) = u;
            }
        } else {
            ushort* my = (ushort*)smem + (tid >> 6) * 16 * CST;
            #pragma unroll
            for (int t = 0; t < 8; ++t) {
                int col = t * 16 + mrow;
                float bv = bias ? bias[col] : 0.f;
                #pragma unroll
                for (int r = 0; r < 4; ++r) {
                    float v = acc[t][r] + bv;
                    if (relu) v = fmaxf(v, 0.f);
                    my[(quad * 4 + r) * CST + col] = f2b(v);
                }
            }
            #pragma unroll
            for (int i = 0; i < 4; ++i) {
                int idx = i * 64 + lane;
                int row = idx >> 4;
                int c16 = idx & 15;
                uint4 u = *(const uint4*)(my + row * CST + c16 * 8);
                *(uint4*)((ushort*)C + (size_t)(row0 + row) * DH + c16 * 8) = u;
            }
        }

        if (DOTS) {
            int orow = row0 + quad * 4;
            #pragma unroll
            for (int r = 0; r < 4; ++r) {
                float ps = 0.f, pd = 0.f;
                #pragma unroll
                for (int t = 0; t < 8; ++t) {
                    ps += acc[t][r] * av[t];
                    pd += acc[t][r] * dv[t];
                }
                #pragma unroll
                for (int off = 1; off < 16; off <<= 1) {
                    ps += __shfl_xor(ps, off);
                    pd += __shfl_xor(pd, off);
                }
                if (mrow == 0) {
                    asrc[orow + r] = ps;
                    adst[orow + r] = pd;
                }
            }
        }
    }
}

// ---------------- GEMM-1: fp32 x -> bf16 hB -------------------------------
__launch_bounds__(256)
__global__ void k_gemm1(const float* __restrict__ x, const ushort* __restrict__ Wt,
                        const float* __restrict__ b0, ushort* __restrict__ hB) {
    __shared__ char smem[SMEM_BYTES];
    gemm_body<true, false, false>(smem, blockIdx.x, x, Wt, b0, hB, 1,
                                  nullptr, nullptr, nullptr, nullptr);
}

// ---------------- GEMM + fused attention dots (layers, fp8 out) ----------
__launch_bounds__(256)
__global__ void k_gemmdots(const ushort* __restrict__ hB, const ushort* __restrict__ Wt,
                           uchar* __restrict__ hA,
                           const float* __restrict__ avs, const float* __restrict__ avd,
                           float* __restrict__ asrc, float* __restrict__ adst) {
    __shared__ char smem[SMEM_BYTES];
    gemm_body<false, true, true>(smem, blockIdx.x, hB, Wt, nullptr, hA, 0,
                                 avs, avd, asrc, adst);
}

// ---------------- single-node aggregate (64-lane, cnt in (32,64]) ----------
__device__ __forceinline__ void aggr_one(int wid, int lane,
        const uchar* __restrict__ h8, const float* __restrict__ asrc,
        const float* __restrict__ adst, const int* __restrict__ cur,
        const ushort* __restrict__ csr,
        const float* __restrict__ bias, ushort* __restrict__ hout) {
    int start = wid << 6;
    int cnt = min(cur[wid] + 1, SEG);
    float ad = adst[wid];

    // masked load: pad lanes use node 0 (w=0 anyway) -> csr pads need no memset
    int s = (lane < cnt) ? (int)csr[start + lane] : 0;
    float e = -1e30f;
    if (lane < cnt) {
        float t = asrc[s] + ad;
        e = fmaxf(t, 0.f) + 0.2f * fminf(t, 0.f);
    }
    float m = e;
    #pragma unroll
    for (int off = 32; off; off >>= 1) m = fmaxf(m, __shfl_xor(m, off));
    float w = (lane < cnt) ? __expf(e - m) : 0.f;
    float dsum = w;
    #pragma unroll
    for (int off = 32; off; off >>= 1) dsum += __shfl_xor(dsum, off);

    int g = lane >> 4, fidx = lane & 15;
    float acc[8];
    #pragma unroll
    for (int k = 0; k < 8; ++k) acc[k] = 0.f;

    int steps = (cnt + 3) >> 2;
    const uint2* hp = (const uint2*)h8;      // 16 uint2 per 128B row
    for (int j = 0; j < steps; ++j) {
        int e0 = j * 4 + g;
        float w0 = __shfl(w, e0);
        int   s0 = __shfl(s, e0);
        uint2 u0 = hp[(size_t)s0 * 16 + fidx];
        float v[8];
        fp8x4_up(u0.x, v); fp8x4_up(u0.y, v + 4);
        #pragma unroll
        for (int k = 0; k < 8; ++k) acc[k] += w0 * v[k];
    }
    #pragma unroll
    for (int k = 0; k < 8; ++k) {
        acc[k] += __shfl_xor(acc[k], 16);
        acc[k] += __shfl_xor(acc[k], 32);
    }
    if (g == 0) {
        float inv = 1.f / (dsum + 1e-16f);
        const float4* bp = (const float4*)bias;
        float4 b0 = bp[fidx * 2], b1 = bp[fidx * 2 + 1];
        uint4 o;
        o.x = pk2(fmaxf(acc[0] * inv + b0.x, 0.f), fmaxf(acc[1] * inv + b0.y, 0.f));
        o.y = pk2(fmaxf(acc[2] * inv + b0.z, 0.f), fmaxf(acc[3] * inv + b0.w, 0.f));
        o.z = pk2(fmaxf(acc[4] * inv + b1.x, 0.f), fmaxf(acc[5] * inv + b1.y, 0.f));
        o.w = pk2(fmaxf(acc[6] * inv + b1.z, 0.f), fmaxf(acc[7] * inv + b1.w, 0.f));
        ((uint4*)hout)[(size_t)wid * 16 + fidx] = o;
    }
}

// ---------------- fused segment softmax + weighted aggregate (fp8 h) -------
// TWO nodes per wave (measured-best round-5 variant): half-wave per node,
// width-32 reductions, 2 gather groups of 16 lanes per half, uint2 gathers
// 4 steps in flight. Rare cnt>32 pairs fall back to the 64-lane path.
__launch_bounds__(256)
__global__ void k_aggr(const uchar* __restrict__ h8, const float* __restrict__ asrc,
                       const float* __restrict__ adst, const int* __restrict__ cur,
                       const ushort* __restrict__ csr,
                       const float* __restrict__ bias, ushort* __restrict__ hout) {
    int pid = (blockIdx.x * blockDim.x + threadIdx.x) >> 6;
    int lane = threadIdx.x & 63;
    if (pid >= NPAIR) return;
    int half = lane >> 5, hl = lane & 31;
    int nd = pid * 2 + half;                     // NN even -> always < NN
    int start = nd << 6;

    int cnt = min(cur[nd] + 1, SEG);
    int cother = __shfl_xor(cnt, 32);            // other half's (uniform) cnt
    if (max(cnt, cother) <= 32) {
        float ad = adst[nd];
        // masked load: pad lanes use node 0 (their w=0) -> no csr memset needed
        int s = (hl < cnt) ? (int)csr[start + hl] : 0;
        float e = -1e30f;
        if (hl < cnt) {
            float t = asrc[s] + ad;
            e = fmaxf(t, 0.f) + 0.2f * fminf(t, 0.f);
        }
        float m = e;
        #pragma unroll
        for (int off = 16; off; off >>= 1) m = fmaxf(m, __shfl_xor(m, off));
        float w = (hl < cnt) ? __expf(e - m) : 0.f;
        float dsum = w;
        #pragma unroll
        for (int off = 16; off; off >>= 1) dsum += __shfl_xor(dsum, off);

        int g = hl >> 4, fidx = hl & 15;         // 2 gather groups per half
        int lbase = half * 32;
        float acc[8];
        #pragma unroll
        for (int k = 0; k < 8; ++k) acc[k] = 0.f;

        int steps = (cnt + 1) >> 1;              // 2 edges/step/node, <=16
        const uint2* hp = (const uint2*)h8;      // 16 uint2 per 128B row
        int j = 0;
        for (; j + 3 < steps; j += 4) {
            int   e0 = j * 2 + g,       e1 = e0 + 2, e2 = e0 + 4, e3 = e0 + 6;
            float w0 = __shfl(w, lbase + e0), w1 = __shfl(w, lbase + e1);
            float w2 = __shfl(w, lbase + e2), w3 = __shfl(w, lbase + e3);
            int   s0 = __shfl(s, lbase + e0), s1 = __shfl(s, lbase + e1);
            int   s2 = __shfl(s, lbase + e2), s3 = __shfl(s, lbase + e3);
            uint2 u0 = hp[(size_t)s0 * 16 + fidx];
            uint2 u1 = hp[(size_t)s1 * 16 + fidx];
            uint2 u2 = hp[(size_t)s2 * 16 + fidx];
            uint2 u3 = hp[(size_t)s3 * 16 + fidx];
            float v[8];
            fp8x4_up(u0.x, v); fp8x4_up(u0.y, v + 4);
            #pragma unroll
            for (int k = 0; k < 8; ++k) acc[k] += w0 * v[k];
            fp8x4_up(u1.x, v); fp8x4_up(u1.y, v + 4);
            #pragma unroll
            for (int k = 0; k < 8; ++k) acc[k] += w1 * v[k];
            fp8x4_up(u2.x, v); fp8x4_up(u2.y, v + 4);
            #pragma unroll
            for (int k = 0; k < 8; ++k) acc[k] += w2 * v[k];
            fp8x4_up(u3.x, v); fp8x4_up(u3.y, v + 4);
            #pragma unroll
            for (int k = 0; k < 8; ++k) acc[k] += w3 * v[k];
        }
        for (; j < steps; ++j) {
            int   e0 = j * 2 + g;
            float w0 = __shfl(w, lbase + e0);
            int   s0 = __shfl(s, lbase + e0);
            uint2 u0 = hp[(size_t)s0 * 16 + fidx];
            float v[8];
            fp8x4_up(u0.x, v); fp8x4_up(u0.y, v + 4);
            #pragma unroll
            for (int k = 0; k < 8; ++k) acc[k] += w0 * v[k];
        }
        #pragma unroll
        for (int k = 0; k < 8; ++k) acc[k] += __shfl_xor(acc[k], 16);   // g0+g1, same half
        if (g == 0) {
            float inv = 1.f / (dsum + 1e-16f);
            const float4* bp = (const float4*)bias;
            float4 b0 = bp[fidx * 2], b1 = bp[fidx * 2 + 1];
            uint4 o;
            o.x = pk2(fmaxf(acc[0] * inv + b0.x, 0.f), fmaxf(acc[1] * inv + b0.y, 0.f));
            o.y = pk2(fmaxf(acc[2] * inv + b0.z, 0.f), fmaxf(acc[3] * inv + b0.w, 0.f));
            o.z = pk2(fmaxf(acc[4] * inv + b1.x, 0.f), fmaxf(acc[5] * inv + b1.y, 0.f));
            o.w = pk2(fmaxf(acc[6] * inv + b1.z, 0.f), fmaxf(acc[7] * inv + b1.w, 0.f));
            ((uint4*)hout)[(size_t)nd * 16 + fidx] = o;
        }
        return;
    }

    // rare: at least one node of the pair exceeds 32 -> sequential 64-lane
    aggr_one(pid * 2,     lane, h8, asrc, adst, cur, csr, bias, hout);
    aggr_one(pid * 2 + 1, lane, h8, asrc, adst, cur, csr, bias, hout);
}

// ---------------- fused mean-pool + final linear (no atomics) --------------
// 64 blocks = 1 graph each. batch is sorted: binary-search the node range,
// reduce 16 rows in flight (short8 loads), LDS-combine, then the 128x10 dot.
__launch_bounds__(256)
__global__ void k_tail(const ushort* __restrict__ h, const int* __restrict__ batch,
                       const float* __restrict__ W1, const float* __restrict__ b1,
                       float* __restrict__ out) {
    __shared__ float sv[16][128];
    int g = blockIdx.x;
    int t = threadIdx.x;

    int a = 0, b = NN;                            // lower_bound(g)
    while (a < b) { int m = (a + b) >> 1; if (batch[m] < g) a = m + 1; else b = m; }
    int lo = a;
    b = NN;                                       // lower_bound(g+1)
    while (a < b) { int m = (a + b) >> 1; if (batch[m] < g + 1) a = m + 1; else b = m; }
    int hi = a;

    int slot = t >> 4;                            // 16 row-slots
    int f8 = (t & 15) * 8;                        // feature group
    float acc[8];
    #pragma unroll
    for (int j = 0; j < 8; ++j) acc[j] = 0.f;
    for (int nd = lo + slot; nd < hi; nd += 16) {
        s16x8 v = *(const s16x8*)(h + (size_t)nd * DH + f8);
        #pragma unroll
        for (int j = 0; j < 8; ++j) acc[j] += b2f((ushort)v[j]);
    }
    #pragma unroll
    for (int j = 0; j < 8; ++j) sv[slot][f8 + j] = acc[j];
    __syncthreads();

    if (t < 128) {
        float s = 0.f;
        #pragma unroll
        for (int k = 0; k < 16; ++k) s += sv[k][t];
        sv[0][t] = s;
    }
    __syncthreads();

    if (t < 10) {
        float inv = 1.f / fmaxf((float)(hi - lo), 1.f);
        float d = 0.f;
        for (int f = 0; f < DH; ++f) d += sv[0][f] * W1[f * 10 + t];
        out[g * 10 + t] = d * inv + b1[t];
    }
}

extern "C" void kernel_launch(void* const* d_in, const int* in_sizes, int n_in,
                              void* d_out, int out_size, void* d_ws, size_t ws_size,
                              hipStream_t stream) {
    const float* x       = (const float*)d_in[0];
    const int*   ei      = (const int*)d_in[1];
    const int*   batch   = (const int*)d_in[3];
    const float* W0      = (const float*)d_in[4];
    const float* b0      = (const float*)d_in[5];
    const float* Wc      = (const float*)d_in[6];
    const float* att_src = (const float*)d_in[7];
    const float* att_dst = (const float*)d_in[8];
    const float* bc      = (const float*)d_in[9];
    const float* W1      = (const float*)d_in[10];
    const float* b1      = (const float*)d_in[11];
    float* out = (float*)d_out;

    char* ws = (char*)d_ws;
    size_t off = 0;
    auto alloc = [&](size_t bytes) {
        void* p = ws + off;
        off += (bytes + 255) & ~(size_t)255;
        return p;
    };
    uchar*    hA     = (uchar*)alloc((size_t)NN * DH);        // fp8 e4m3
    ushort*   hB     = (ushort*)alloc((size_t)NN * DH * 2);   // bf16
    ushort*   Wt     = (ushort*)alloc((size_t)4 * DH * DH * 2);
    ushort*   csr    = (ushort*)alloc((size_t)NN * SEG * 2);  // fixed-stride segments (no memset: pads masked)
    int*      cur    = (int*)alloc((size_t)NN * 4);           // 0-based edge count
    float*    asrc   = (float*)alloc(NN * 4);
    float*    adst   = (float*)alloc(NN * 4);

    hipMemsetAsync(cur, 0, (size_t)NN * 4, stream);           // only cur needs zeroing

    k_prep<<<PREPB, 256, 0, stream>>>(ei, cur, csr, W0, Wc, Wt);
    k_gemm1<<<GEMMB, 256, 0, stream>>>(x, Wt, b0, hB);

    for (int l = 0; l < 3; ++l) {
        k_gemmdots<<<GEMMB, 256, 0, stream>>>(hB, Wt + (size_t)(l + 1) * DH * DH, hA,
                                              att_src + l * DH, att_dst + l * DH,
                                              asrc, adst);
        k_aggr<<<(NPAIR + 3) / 4, 256, 0, stream>>>(hA, asrc, adst, cur, csr,
                                                    bc + l * DH, hB);
    }

    k_tail<<<NG, 256, 0, stream>>>(hB, batch, W1, b1, out);
}